// Round 8
// baseline (267.805 us; speedup 1.0000x reference)
//
#include <hip/hip_runtime.h>

// ---------------------------------------------------------------------------
// MultiHeadAttention: B=4, S=2048, NH=16, HD=64, H=1024
// Pipeline (all bf16 MFMA, fp32 accumulate):
//   1) prep_all (fused): X -> bf16; Wqkv^T -> bf16 with softmax scale
//      (0.125*log2e) folded into Q columns; Wout^T -> bf16; mask -> bias;
//      mask -> compacted tile list (bias/tl in __device__ globals).
//   2) QKV = X @ Wqkv, R8: 256x256 tile, BK=64, 8 waves/512thr, 128KB LDS
//      double-buffer, PREFETCH DISTANCE 2 with counted vmcnt(8) (never
//      drained in-loop), raw s_barrier, setprio on MFMA clusters, XCD
//      swizzle. A/B staged [ks][256][32] (64B rows -> conflict-free b128
//      frag reads, no XOR swizzle needed). Epilogue repack reuses LDS.
//      (R7's 2ph counted-vmcnt at 128^2 was NULL - matches catalog regime
//      gate: only the 256^2 deep-pipeline structure breaks the ceiling.)
//   3) flash attention (R4 version - best measured 82 us): 4 waves/256thr,
//      64 q-rows/wave, grid (64,8); operand-swap (S^T = mfma(K,Q)); compacted
//      tile list; 1-barrier double-buffered KV staging with register
//      prefetch; V column-permuted in LDS (PV B-fragment = 1 ds_read_b128);
//      packed bf16 P; row-sums via MFMA vs ones; rcp epilogue.
//      History: R1/R2 (occupancy variants) regressed; R5 (no-LDS) latency
//      disaster. LDS staging is the latency hider; structure pinned.
//   4) out = Aout @ Wout + bout (R4 single-buffer 128^2 kernel - proven)
// Workspace 72 MB: Xbf 16 (Aout alias) | WqkvT 6 | WoutT 2 | QK 32 | Vt 16
// ---------------------------------------------------------------------------

typedef short bh8 __attribute__((ext_vector_type(8)));
typedef short bh4 __attribute__((ext_vector_type(4)));
typedef float f32x4 __attribute__((ext_vector_type(4)));

#define B_ 4
#define S_ 2048
#define NH_ 16
#define HD_ 64
#define H_ 1024

__device__ float g_biasf[B_ * S_];
__device__ int g_tl[B_ * 33];

__device__ inline short f2bf(float f) {
    unsigned u = __builtin_bit_cast(unsigned, f);
    u = (u + 0x7fffu + ((u >> 16) & 1u)) >> 16;  // RTNE
    return (short)u;
}

// pack two f32 -> two bf16 in one dword (low = a, high = b)
__device__ inline unsigned pk2bf(float a, float b) {
#if __has_builtin(__builtin_amdgcn_cvt_pk_bf16_f32)
    auto r = __builtin_amdgcn_cvt_pk_bf16_f32(a, b);
    return __builtin_bit_cast(unsigned, r);
#else
    unsigned ua = __builtin_bit_cast(unsigned, a) + 0x8000u;  // round-half-up
    unsigned ub = __builtin_bit_cast(unsigned, b) + 0x8000u;
    return __builtin_amdgcn_perm(ub, ua, 0x07060302);  // [ua2,ua3,ub2,ub3]
#endif
}

// ------------------- fused prep: cvt + 2 transposes + bias + tilelist ------
// block ranges: [0,8192) cvt X | [8192,11264) Wqkv^T | [11264,12288) Wout^T |
//               [12288,12320) bias | [12320,12324) tilelist
__global__ void prep_all(const float* __restrict__ hidden, const float* __restrict__ Wqkv,
                         const float* __restrict__ Wout, const int* __restrict__ mask,
                         short* __restrict__ Xbf, short* __restrict__ WqkvT,
                         short* __restrict__ WoutT, float qs) {
    __shared__ float tile[32][33];
    int bi = blockIdx.x, tid = threadIdx.x;

    if (bi < 8192) {  // ---- X fp32 -> bf16
        int i = (bi * 256 + tid) * 4;
        float4 v = *(const float4*)(hidden + i);
        union { short s[4]; unsigned long long u; } r;
        r.s[0] = f2bf(v.x); r.s[1] = f2bf(v.y); r.s[2] = f2bf(v.z); r.s[3] = f2bf(v.w);
        *(unsigned long long*)(Xbf + i) = r.u;
        return;
    }
    if (bi < 12288) {  // ---- weight transpose+cvt (32x32 tiles, 256 thr)
        const float* in; short* out; int N, qcols, idx;
        if (bi < 11264) { in = Wqkv; out = WqkvT; N = 3 * H_; qcols = H_; idx = bi - 8192;
        } else          { in = Wout; out = WoutT; N = H_;    qcols = 0;  idx = bi - 11264; }
        int xt = (bi < 11264) ? 96 : 32;
        int n0 = (idx % xt) * 32, k0 = (idx / xt) * 32;
        int tx = tid & 31, ty = tid >> 5;  // (32,8)
#pragma unroll
        for (int i = 0; i < 32; i += 8)
            tile[ty + i][tx] = in[(long)(k0 + ty + i) * N + n0 + tx];
        __syncthreads();
#pragma unroll
        for (int i = 0; i < 32; i += 8) {
            int n = n0 + ty + i;
            float v = tile[tx][ty + i];
            if (n < qcols) v *= qs;
            out[(long)n * H_ + k0 + tx] = f2bf(v);
        }
        return;
    }
    if (bi < 12320) {  // ---- mask -> additive bias
        int i = (bi - 12288) * 256 + tid;
        g_biasf[i] = mask[i] ? 0.0f : -1e30f;
        return;
    }
    {  // ---- tilelist: 4 blocks, wave 0 only (ballot is wave-wide = 64)
        int b = bi - 12320;
        if (tid < 64) {
            int t = tid, flag = 0;
            if (t < 32) {
                bool anyA = false, anyM = false;
                for (int i = 0; i < 64; ++i) {
                    int m = mask[b * S_ + t * 64 + i];
                    anyA |= (m != 0); anyM |= (m == 0);
                }
                flag = anyA ? (anyM ? 1 : 2) : 0;
            }
            unsigned long long act = __ballot(flag != 0);
            int pos = __popcll(act & ((1ull << t) - 1ull));
            if (flag) g_tl[b * 33 + 1 + pos] = t | (flag << 16);
            if (t == 0) g_tl[b * 33] = __popcll(act);
        }
    }
}

// --------------------- QKV GEMM: 256x256 deep pipeline ---------------------
// Grid (12,32) XCD-swizzled; M=8192 N=3072 K=1024. LDS per K-tile buffer:
// A [ks(2)][256 rows][32 shorts] (16384 shorts) then B same (16384);
// two buffers = 65536 shorts = 128KB. Staging: 8 global_load_lds calls of
// 16B/lane per K-tile (A 4 + B 4); gload j writes LDS linear j*4096+tid*8
// == [j>>1][ (j&1)*128 + tid>>2 ][ tid&3 ] -- layout matches by construction.
__device__ inline void stage256(const short* Ag, const short* Bg, int k0,
                                short* dst, int tid, int wid) {
#pragma unroll
    for (int j = 0; j < 4; ++j) {
        int row = (j & 1) * 128 + (tid >> 2);
        int col = k0 + (j >> 1) * 32 + (tid & 3) * 8;
        __builtin_amdgcn_global_load_lds(
            (const __attribute__((address_space(1))) void*)(Ag + (long)row * 1024 + col),
            (__attribute__((address_space(3))) void*)(dst + j * 4096 + wid * 512),
            16, 0, 0);
        __builtin_amdgcn_global_load_lds(
            (const __attribute__((address_space(1))) void*)(Bg + (long)row * 1024 + col),
            (__attribute__((address_space(3))) void*)(dst + 16384 + j * 4096 + wid * 512),
            16, 0, 0);
    }
}

__global__ __launch_bounds__(512, 2) void gemm_qkv(
    const short* __restrict__ A, const short* __restrict__ Bt,
    short* __restrict__ qk, short* __restrict__ vt) {
    __shared__ short smem[65536];  // 128 KB
    const int NT = 16;             // K=1024 / 64
    int tid = threadIdx.x;
    int lane = tid & 63, wid = tid >> 6;
    int quad = lane >> 4, l15 = lane & 15;
    int wr = wid >> 2, wc = wid & 3;           // wave tile 128x64
    int lin = blockIdx.y * 12 + blockIdx.x;    // 384 blocks, 384%8==0
    int swz = (lin & 7) * 48 + (lin >> 3);     // bijective XCD swizzle
    int m0 = (swz / 12) * 256, n0 = (swz % 12) * 256;

    const short* Ag = A + (long)m0 * 1024;
    const short* Bg = Bt + (long)n0 * 1024;

    f32x4 acc[8][4] = {};

    // prologue: tiles 0,1 in flight (16 loads); wait tile0 (oldest 8)
    stage256(Ag, Bg, 0, smem, tid, wid);
    stage256(Ag, Bg, 64, smem + 32768, tid, wid);
    asm volatile("s_waitcnt vmcnt(8)" ::: "memory");
    __builtin_amdgcn_s_barrier();

    for (int t = 0; t < NT; ++t) {
        const short* sA = smem + (t & 1) * 32768;
        const short* sB = sA + 16384;
        // ks = 0 fragments + MFMA
        bh8 a0[8], b0[4];
#pragma unroll
        for (int mi = 0; mi < 8; ++mi)
            a0[mi] = *(const bh8*)(sA + (wr * 128 + mi * 16 + l15) * 32 + quad * 8);
#pragma unroll
        for (int ni = 0; ni < 4; ++ni)
            b0[ni] = *(const bh8*)(sB + (wc * 64 + ni * 16 + l15) * 32 + quad * 8);
        __builtin_amdgcn_s_setprio(1);
#pragma unroll
        for (int mi = 0; mi < 8; ++mi)
#pragma unroll
            for (int ni = 0; ni < 4; ++ni)
                acc[mi][ni] = __builtin_amdgcn_mfma_f32_16x16x32_bf16(a0[mi], b0[ni], acc[mi][ni], 0, 0, 0);
        __builtin_amdgcn_s_setprio(0);
        // ks = 1 fragments
        bh8 a1[8], b1[4];
#pragma unroll
        for (int mi = 0; mi < 8; ++mi)
            a1[mi] = *(const bh8*)(sA + 8192 + (wr * 128 + mi * 16 + l15) * 32 + quad * 8);
#pragma unroll
        for (int ni = 0; ni < 4; ++ni)
            b1[ni] = *(const bh8*)(sB + 8192 + (wc * 64 + ni * 16 + l15) * 32 + quad * 8);
        // all reads of this buffer done (this wave: lgkm; all waves: barrier)
        asm volatile("s_waitcnt lgkmcnt(0)" ::: "memory");
        __builtin_amdgcn_sched_barrier(0);
        __builtin_amdgcn_s_barrier();
        // overwrite-stage tile t+2 into the buffer just vacated
        if (t + 2 < NT)
            stage256(Ag, Bg, (t + 2) << 6, smem + (t & 1) * 32768, tid, wid);
        __builtin_amdgcn_s_setprio(1);
#pragma unroll
        for (int mi = 0; mi < 8; ++mi)
#pragma unroll
            for (int ni = 0; ni < 4; ++ni)
                acc[mi][ni] = __builtin_amdgcn_mfma_f32_16x16x32_bf16(a1[mi], b1[ni], acc[mi][ni], 0, 0, 0);
        __builtin_amdgcn_s_setprio(0);
        // tile t+1 must be landed before next iter reads it:
        // in-flight = {t+1:8, t+2:8} -> vmcnt(8); tail: only {t+1:8} -> vmcnt(0)
        if (t + 2 < NT)      { asm volatile("s_waitcnt vmcnt(8)" ::: "memory"); }
        else if (t + 1 < NT) { asm volatile("s_waitcnt vmcnt(0)" ::: "memory"); }
        __builtin_amdgcn_s_barrier();
    }

    // epilogue: repack 256x256 through LDS (reuses staging space)
    __syncthreads();
    bool isV = (n0 >= 2048);
    if (!isV) {
#pragma unroll
        for (int mi = 0; mi < 8; ++mi)
#pragma unroll
            for (int ni = 0; ni < 4; ++ni) {
                int r = wr * 128 + mi * 16 + quad * 4;
                int c = wc * 64 + ni * 16 + l15;
#pragma unroll
                for (int reg = 0; reg < 4; ++reg)
                    smem[(r + reg) * 256 + c] = f2bf(acc[mi][ni][reg]);  // [row][col]
            }
    } else {
#pragma unroll
        for (int mi = 0; mi < 8; ++mi)
#pragma unroll
            for (int ni = 0; ni < 4; ++ni) {
                int r = wr * 128 + mi * 16 + quad * 4;
                int c = wc * 64 + ni * 16 + l15;
                unsigned lo = pk2bf(acc[mi][ni][0], acc[mi][ni][1]);
                unsigned hi = pk2bf(acc[mi][ni][2], acc[mi][ni][3]);
                uint2 uu = {lo, hi};
                *(bh4*)(smem + c * 256 + r) = __builtin_bit_cast(bh4, uu);  // [col][row]
            }
    }
    __syncthreads();
    int bb = m0 >> 11, sbase = m0 & 2047;
#pragma unroll
    for (int j = 0; j < 16; ++j) {
        int cj = j * 512 + tid;
        int i0 = cj >> 5, i1 = (cj & 31) << 3;
        bh8 v = *(const bh8*)(smem + i0 * 256 + i1);
        if (isV) {
            int cc = n0 - 2048 + i0;
            int h = cc >> 6, d = cc & 63;
            *(bh8*)(vt + ((long)(bb * NH_ + h) * HD_ + d) * S_ + sbase + i1) = v;
        } else {
            *(bh8*)(qk + (long)(m0 + i0) * 2048 + n0 + i1) = v;
        }
    }
}

// --------------------- out GEMM (R4 proven 128x128 core) -------------------
__global__ __launch_bounds__(256, 2) void gemm_out(
    const short* __restrict__ A, const short* __restrict__ Bt,
    int N, int K, const float* __restrict__ bias, float* __restrict__ out) {
    __shared__ short smem[128 * 136];
    short* sA[2] = { smem, smem + 4096 };
    short* sB[2] = { smem + 8192, smem + 12288 };
    int tid = threadIdx.x;
    int lane = tid & 63, wid = tid >> 6;
    int quad = lane >> 4, l15 = lane & 15;
    int wy = wid >> 1, wx = wid & 1;
    int m0 = blockIdx.y * 128, n0 = blockIdx.x * 128;

    f32x4 acc[4][4] = {};
    const short* Ag = A + (long)m0 * K;
    const short* Bg = Bt + (long)n0 * K;

    for (int k0 = 0; k0 < K; k0 += 64) {
#pragma unroll
        for (int half = 0; half < 2; ++half) {
#pragma unroll
            for (int i = 0; i < 2; ++i) {
                int flat = i * 256 + tid;
                int r = flat >> 2, c = (flat & 3) << 3;
                __builtin_amdgcn_global_load_lds(
                    (const __attribute__((address_space(1))) void*)(Ag + (long)r * K + k0 + half * 32 + c),
                    (__attribute__((address_space(3))) void*)(sA[half] + i * 2048 + wid * 512),
                    16, 0, 0);
                __builtin_amdgcn_global_load_lds(
                    (const __attribute__((address_space(1))) void*)(Bg + (long)r * K + k0 + half * 32 + c),
                    (__attribute__((address_space(3))) void*)(sB[half] + i * 2048 + wid * 512),
                    16, 0, 0);
            }
        }
        __syncthreads();
#pragma unroll
        for (int half = 0; half < 2; ++half) {
            bh8 af[4], bfr[4];
#pragma unroll
            for (int mi = 0; mi < 4; ++mi)
                af[mi] = *(const bh8*)(sA[half] + (wy * 64 + mi * 16 + l15) * 32 + quad * 8);
#pragma unroll
            for (int ni = 0; ni < 4; ++ni)
                bfr[ni] = *(const bh8*)(sB[half] + (wx * 64 + ni * 16 + l15) * 32 + quad * 8);
#pragma unroll
            for (int mi = 0; mi < 4; ++mi)
#pragma unroll
                for (int ni = 0; ni < 4; ++ni)
                    acc[mi][ni] = __builtin_amdgcn_mfma_f32_16x16x32_bf16(af[mi], bfr[ni], acc[mi][ni], 0, 0, 0);
        }
        __syncthreads();
    }

#pragma unroll
    for (int mi = 0; mi < 4; ++mi)
#pragma unroll
        for (int ni = 0; ni < 4; ++ni) {
            int gc = n0 + wx * 64 + ni * 16 + l15;
            float bv = bias[gc];
#pragma unroll
            for (int reg = 0; reg < 4; ++reg) {
                int gr = m0 + wy * 64 + mi * 16 + quad * 4 + reg;
                out[(long)gr * N + gc] = acc[mi][ni][reg] + bv;
            }
        }
}

// ---------------------------- flash attention ------------------------------
// R4 version (best measured): 64 q-rows/wave, 4 waves, grid (64,8) = 512
// blocks = 2/CU. V stored column-permuted in LDS: s=(pr,q16,quad,e) ->
// idx=(pr,quad,q16,e) so the PV B-fragment is one ds_read_b128.
__global__ __launch_bounds__(256, 2) void attn_fwd(
    const short* __restrict__ QK, const short* __restrict__ Vtw,
    short* __restrict__ Aout) {
    __shared__ short lK[2][64 * 72];
    __shared__ short lV[2][64 * 72];
    int tid = threadIdx.x;
    int lane = tid & 63, w = tid >> 6;
    int quad = lane >> 4, l15 = lane & 15;
    int p = blockIdx.x;
    int b = p >> 4, h = p & 15;
    int qbase = blockIdx.y * 256 + w * 64;

    const short* Kb = QK + (long)b * S_ * 2048 + 1024 + h * HD_;
    const short* Vb = Vtw + (long)p * HD_ * S_;

    // staging geometry, hoisted: thread stages rows r0 and r0+32, 8 cols each
    int r0 = tid >> 3, g = tid & 7, c = g << 3;
    int voff = (g >> 2) * 32 + (g & 1) * 16 + ((g >> 1) & 1) * 4;  // perm dest
    const short* Kp0 = Kb + (long)r0 * 2048 + c;      // + j0*2048 per tile
    const short* Kp1 = Kp0 + 32l * 2048;
    const short* Vp0 = Vb + (long)r0 * S_ + c;        // + j0 per tile
    const short* Vp1 = Vp0 + 32l * S_;

    // Q fragments (pre-scaled by 0.125*log2e at weight-transpose time)
    bh8 qf[4][2];
#pragma unroll
    for (int mi = 0; mi < 4; ++mi)
#pragma unroll
        for (int ks = 0; ks < 2; ++ks)
            qf[mi][ks] = *(const bh8*)(QK + (long)(b * S_ + qbase + mi * 16 + l15) * 2048
                                       + h * HD_ + ks * 32 + quad * 8);

    f32x4 o[4][4] = {};
    f32x4 ls[4] = {};
    const bh8 ones = {0x3F80, 0x3F80, 0x3F80, 0x3F80, 0x3F80, 0x3F80, 0x3F80, 0x3F80};

    int cnt = g_tl[b * 33];
    int e0 = g_tl[b * 33 + 1];
    int j0 = (e0 & 0xffff) << 6, flag = e0 >> 16;
    bh8 kp[2], vp[2];
    kp[0] = *(const bh8*)(Kp0 + (long)j0 * 2048);
    kp[1] = *(const bh8*)(Kp1 + (long)j0 * 2048);
    vp[0] = *(const bh8*)(Vp0 + j0);
    vp[1] = *(const bh8*)(Vp1 + j0);
    {
        *(bh8*)(lK[0] + r0 * 72 + c) = kp[0];
        *(bh8*)(lK[0] + (r0 + 32) * 72 + c) = kp[1];
        *(bh4*)(lV[0] + r0 * 72 + voff)            = __builtin_shufflevector(vp[0], vp[0], 0, 1, 2, 3);
        *(bh4*)(lV[0] + r0 * 72 + voff + 8)        = __builtin_shufflevector(vp[0], vp[0], 4, 5, 6, 7);
        *(bh4*)(lV[0] + (r0 + 32) * 72 + voff)     = __builtin_shufflevector(vp[1], vp[1], 0, 1, 2, 3);
        *(bh4*)(lV[0] + (r0 + 32) * 72 + voff + 8) = __builtin_shufflevector(vp[1], vp[1], 4, 5, 6, 7);
    }
    int cur = 0;

    for (int it = 0; it < cnt; ++it) {
        __syncthreads();  // buf[cur] writes visible; prior readers of buf[cur^1] done
        bool more = (it + 1 < cnt);
        int nj0 = 0, nflag = 0;
        if (more) {
            int en = g_tl[b * 33 + 2 + it];
            nj0 = (en & 0xffff) << 6; nflag = en >> 16;
            kp[0] = *(const bh8*)(Kp0 + (long)nj0 * 2048);   // prefetch overlaps
            kp[1] = *(const bh8*)(Kp1 + (long)nj0 * 2048);   // compute below
            vp[0] = *(const bh8*)(Vp0 + nj0);
            vp[1] = *(const bh8*)(Vp1 + nj0);
        }
        const short* ck = lK[cur];
        const short* cv = lV[cur];

        // S^T = K @ Q^T per 16-key subtile; exp2 -> P fragments in A-layout
        bh4 pf[4][4];  // [nj][mi]
#pragma unroll
        for (int nj = 0; nj < 4; ++nj) {
            f32x4 scn[4] = {};
#pragma unroll
            for (int ks = 0; ks < 2; ++ks) {
                bh8 kf = *(const bh8*)(ck + (nj * 16 + l15) * 72 + ks * 32 + quad * 8);
#pragma unroll
                for (int mi = 0; mi < 4; ++mi)
                    scn[mi] = __builtin_amdgcn_mfma_f32_16x16x32_bf16(kf, qf[mi][ks], scn[mi], 0, 0, 0);
            }
            if (flag == 1) {
                f32x4 bb = *(const f32x4*)(g_biasf + b * S_ + j0 + nj * 16 + quad * 4);
#pragma unroll
                for (int mi = 0; mi < 4; ++mi) {
#pragma unroll
                    for (int r = 0; r < 4; ++r) scn[mi][r] += bb[r];
                }
            }
#pragma unroll
            for (int mi = 0; mi < 4; ++mi) {
                unsigned u0 = pk2bf(__builtin_amdgcn_exp2f(scn[mi][0]),
                                    __builtin_amdgcn_exp2f(scn[mi][1]));
                unsigned u1 = pk2bf(__builtin_amdgcn_exp2f(scn[mi][2]),
                                    __builtin_amdgcn_exp2f(scn[mi][3]));
                uint2 uu = {u0, u1};
                pf[nj][mi] = __builtin_bit_cast(bh4, uu);
            }
        }

        // O += P @ V, ls += P @ ones (two 16-key subtiles per K=32 mfma)
#pragma unroll
        for (int pr = 0; pr < 2; ++pr) {
            int njA = 2 * pr, njB = 2 * pr + 1;
            bh8 a[4];
#pragma unroll
            for (int mi = 0; mi < 4; ++mi)
                a[mi] = __builtin_shufflevector(pf[njA][mi], pf[njB][mi], 0, 1, 2, 3, 4, 5, 6, 7);
            __builtin_amdgcn_s_setprio(1);
#pragma unroll
            for (int mi = 0; mi < 4; ++mi)
                ls[mi] = __builtin_amdgcn_mfma_f32_16x16x32_bf16(a[mi], ones, ls[mi], 0, 0, 0);
#pragma unroll
            for (int nd = 0; nd < 4; ++nd) {
                // permuted layout: one b128 = old concat(v0, v1)
                bh8 vf = *(const bh8*)(cv + (nd * 16 + l15) * 72 + pr * 32 + quad * 8);
#pragma unroll
                for (int mi = 0; mi < 4; ++mi)
                    o[mi][nd] = __builtin_amdgcn_mfma_f32_16x16x32_bf16(a[mi], vf, o[mi][nd], 0, 0, 0);
            }
            __builtin_amdgcn_s_setprio(0);
        }

        if (more) {
            short* lk = lK[cur ^ 1];
            short* lv = lV[cur ^ 1];
            *(bh8*)(lk + r0 * 72 + c) = kp[0];
            *(bh8*)(lk + (r0 + 32) * 72 + c) = kp[1];
            *(bh4*)(lv + r0 * 72 + voff)            = __builtin_shufflevector(vp[0], vp[0], 0, 1, 2, 3);
            *(bh4*)(lv + r0 * 72 + voff + 8)        = __builtin_shufflevector(vp[0], vp[0], 4, 5, 6, 7);
            *(bh4*)(lv + (r0 + 32) * 72 + voff)     = __builtin_shufflevector(vp[1], vp[1], 0, 1, 2, 3);
            *(bh4*)(lv + (r0 + 32) * 72 + voff + 8) = __builtin_shufflevector(vp[1], vp[1], 4, 5, 6, 7);
        }
        j0 = nj0; flag = nflag; cur ^= 1;
    }

    // Aout[b][s][h*64+d] = O * (1/ls)  (rcp is fine: output is bf16-rounded)
#pragma unroll
    for (int mi = 0; mi < 4; ++mi)
#pragma unroll
        for (int reg = 0; reg < 4; ++reg) {
            float inv = __builtin_amdgcn_rcpf(ls[mi][reg]);
            int s = qbase + mi * 16 + quad * 4 + reg;
#pragma unroll
            for (int nd = 0; nd < 4; ++nd) {
                int col = h * HD_ + nd * 16 + l15;
                Aout[((long)b * S_ + s) * H_ + col] = f2bf(o[mi][nd][reg] * inv);
            }
        }
}

// ------------------------------- launcher ----------------------------------
extern "C" void kernel_launch(void* const* d_in, const int* in_sizes, int n_in,
                              void* d_out, int out_size, void* d_ws, size_t ws_size,
                              hipStream_t stream) {
    const float* hidden = (const float*)d_in[0];
    const int* mask = (const int*)d_in[1];
    const float* Wqkv = (const float*)d_in[2];
    const float* Wout = (const float*)d_in[3];
    const float* bout = (const float*)d_in[4];
    float* out = (float*)d_out;

    char* ws = (char*)d_ws;
    const size_t XBF = 0;                       // 16 MB (Aout alias)
    const size_t WQKVT = 16777216;              // 6 MB
    const size_t WOUTT = WQKVT + 6291456;       // 2 MB
    const size_t QKO = WOUTT + 2097152;         // 32 MB: QK[8192][2048]
    const size_t VT = QKO + 33554432;           // 16 MB: Vt (end 72 MB)

    short* Xbf = (short*)(ws + XBF);
    short* WqkvT = (short*)(ws + WQKVT);
    short* WoutT = (short*)(ws + WOUTT);
    short* QK = (short*)(ws + QKO);
    short* Vt = (short*)(ws + VT);
    short* Aout = Xbf;                            // Xbf dead after QKV GEMM

    const float Cs = 0.18033688011112042f;  // (1/8) * log2(e), folded into Q

    // fused prep: cvt + Wqkv^T + Wout^T + bias + tilelist (1 launch)
    prep_all<<<dim3(12324), dim3(256), 0, stream>>>(
        hidden, Wqkv, Wout, mask, Xbf, WqkvT, WoutT, Cs);

    // QKV projection: M=8192, N=3072, K=1024 (256^2 deep-pipelined)
    gemm_qkv<<<dim3(12, 32), dim3(512), 0, stream>>>(Xbf, WqkvT, QK, Vt);

    attn_fwd<<<dim3(64, 8), dim3(256), 0, stream>>>(QK, Vt, Aout);

    // Output projection: M=8192, N=1024, K=1024 (+bias, fp32 out)
    gemm_out<<<dim3(8, 64), dim3(256), 0, stream>>>(
        Aout, WoutT, H_, H_, bout, out);
}

// Round 9
// 264.272 us; speedup vs baseline: 1.0134x; 1.0134x over previous
//
#include <hip/hip_runtime.h>

// ---------------------------------------------------------------------------
// MultiHeadAttention: B=4, S=2048, NH=16, HD=64, H=1024
// Pipeline (all bf16 MFMA, fp32 accumulate):
//   1) prep_all (fused): X -> bf16; Wqkv^T -> bf16 with softmax scale
//      (0.125*log2e) folded into Q columns; Wout^T -> bf16; mask -> bias;
//      mask -> compacted tile list (bias/tl in __device__ globals).
//   2) QKV = X @ Wqkv, R9: 256x256 tile, BK=64, 8 waves/512thr, 128KB LDS
//      double-buffer, prefetch distance 2, counted vmcnt(8), raw s_barrier,
//      setprio, XCD swizzle + NEW: chunk XOR-swizzle (chunk ^= (row>>1)&3).
//      R8 measured 7.2M bank conflicts (4-way on every b128 fragment read:
//      64B rows -> bank = (row%2)*16 + chunk*4, 8 rows/quad share a chunk).
//      Swizzle applied BOTH sides: linear LDS dest + pre-swizzled global
//      SOURCE column (involution) + swizzled read addr (catalog rule 21).
//   3) flash attention (R4 version - best measured 82 us): structure pinned
//      (R1/R2 occupancy variants and R5 no-LDS all regressed).
//   4) out = Aout @ Wout + bout (R4 128^2 core + same read-swizzle fix)
// Workspace 72 MB: Xbf 16 (Aout alias) | WqkvT 6 | WoutT 2 | QK 32 | Vt 16
// ---------------------------------------------------------------------------

typedef short bh8 __attribute__((ext_vector_type(8)));
typedef short bh4 __attribute__((ext_vector_type(4)));
typedef float f32x4 __attribute__((ext_vector_type(4)));

#define B_ 4
#define S_ 2048
#define NH_ 16
#define HD_ 64
#define H_ 1024

__device__ float g_biasf[B_ * S_];
__device__ int g_tl[B_ * 33];

__device__ inline short f2bf(float f) {
    unsigned u = __builtin_bit_cast(unsigned, f);
    u = (u + 0x7fffu + ((u >> 16) & 1u)) >> 16;  // RTNE
    return (short)u;
}

// pack two f32 -> two bf16 in one dword (low = a, high = b)
__device__ inline unsigned pk2bf(float a, float b) {
#if __has_builtin(__builtin_amdgcn_cvt_pk_bf16_f32)
    auto r = __builtin_amdgcn_cvt_pk_bf16_f32(a, b);
    return __builtin_bit_cast(unsigned, r);
#else
    unsigned ua = __builtin_bit_cast(unsigned, a) + 0x8000u;  // round-half-up
    unsigned ub = __builtin_bit_cast(unsigned, b) + 0x8000u;
    return __builtin_amdgcn_perm(ub, ua, 0x07060302);  // [ua2,ua3,ub2,ub3]
#endif
}

// ------------------- fused prep: cvt + 2 transposes + bias + tilelist ------
// block ranges: [0,8192) cvt X | [8192,11264) Wqkv^T | [11264,12288) Wout^T |
//               [12288,12320) bias | [12320,12324) tilelist
__global__ void prep_all(const float* __restrict__ hidden, const float* __restrict__ Wqkv,
                         const float* __restrict__ Wout, const int* __restrict__ mask,
                         short* __restrict__ Xbf, short* __restrict__ WqkvT,
                         short* __restrict__ WoutT, float qs) {
    __shared__ float tile[32][33];
    int bi = blockIdx.x, tid = threadIdx.x;

    if (bi < 8192) {  // ---- X fp32 -> bf16
        int i = (bi * 256 + tid) * 4;
        float4 v = *(const float4*)(hidden + i);
        union { short s[4]; unsigned long long u; } r;
        r.s[0] = f2bf(v.x); r.s[1] = f2bf(v.y); r.s[2] = f2bf(v.z); r.s[3] = f2bf(v.w);
        *(unsigned long long*)(Xbf + i) = r.u;
        return;
    }
    if (bi < 12288) {  // ---- weight transpose+cvt (32x32 tiles, 256 thr)
        const float* in; short* out; int N, qcols, idx;
        if (bi < 11264) { in = Wqkv; out = WqkvT; N = 3 * H_; qcols = H_; idx = bi - 8192;
        } else          { in = Wout; out = WoutT; N = H_;    qcols = 0;  idx = bi - 11264; }
        int xt = (bi < 11264) ? 96 : 32;
        int n0 = (idx % xt) * 32, k0 = (idx / xt) * 32;
        int tx = tid & 31, ty = tid >> 5;  // (32,8)
#pragma unroll
        for (int i = 0; i < 32; i += 8)
            tile[ty + i][tx] = in[(long)(k0 + ty + i) * N + n0 + tx];
        __syncthreads();
#pragma unroll
        for (int i = 0; i < 32; i += 8) {
            int n = n0 + ty + i;
            float v = tile[tx][ty + i];
            if (n < qcols) v *= qs;
            out[(long)n * H_ + k0 + tx] = f2bf(v);
        }
        return;
    }
    if (bi < 12320) {  // ---- mask -> additive bias
        int i = (bi - 12288) * 256 + tid;
        g_biasf[i] = mask[i] ? 0.0f : -1e30f;
        return;
    }
    {  // ---- tilelist: 4 blocks, wave 0 only (ballot is wave-wide = 64)
        int b = bi - 12320;
        if (tid < 64) {
            int t = tid, flag = 0;
            if (t < 32) {
                bool anyA = false, anyM = false;
                for (int i = 0; i < 64; ++i) {
                    int m = mask[b * S_ + t * 64 + i];
                    anyA |= (m != 0); anyM |= (m == 0);
                }
                flag = anyA ? (anyM ? 1 : 2) : 0;
            }
            unsigned long long act = __ballot(flag != 0);
            int pos = __popcll(act & ((1ull << t) - 1ull));
            if (flag) g_tl[b * 33 + 1 + pos] = t | (flag << 16);
            if (t == 0) g_tl[b * 33] = __popcll(act);
        }
    }
}

// --------------------- QKV GEMM: 256x256 deep pipeline ---------------------
// LDS logical layout [ks][256 rows][4 chunks x 8 shorts], chunk XOR-swizzled:
// LDS[row][c] holds global[row][c ^ ((row>>1)&3)]. Staging keeps the linear
// LDS dest (gload_lds) and pre-swizzles the SOURCE column; reads XOR the
// chunk. Involution => read returns the un-swizzled data. Conflict-free:
// per 8-lane beat, banks (row%2)*16 + ((quad^((row>>1)&3))*4) cover all 32.
__device__ inline void stage256(const short* Ag, const short* Bg, int k0,
                                short* dst, int tid, int wid) {
#pragma unroll
    for (int j = 0; j < 4; ++j) {
        int row = (j & 1) * 128 + (tid >> 2);
        int chunk = (tid & 3) ^ ((tid >> 3) & 3);  // (row>>1)&3 == (tid>>3)&3
        int col = k0 + (j >> 1) * 32 + chunk * 8;
        __builtin_amdgcn_global_load_lds(
            (const __attribute__((address_space(1))) void*)(Ag + (long)row * 1024 + col),
            (__attribute__((address_space(3))) void*)(dst + j * 4096 + wid * 512),
            16, 0, 0);
        __builtin_amdgcn_global_load_lds(
            (const __attribute__((address_space(1))) void*)(Bg + (long)row * 1024 + col),
            (__attribute__((address_space(3))) void*)(dst + 16384 + j * 4096 + wid * 512),
            16, 0, 0);
    }
}

__global__ __launch_bounds__(512, 2) void gemm_qkv(
    const short* __restrict__ A, const short* __restrict__ Bt,
    short* __restrict__ qk, short* __restrict__ vt) {
    __shared__ short smem[65536];  // 128 KB
    const int NT = 16;             // K=1024 / 64
    int tid = threadIdx.x;
    int lane = tid & 63, wid = tid >> 6;
    int quad = lane >> 4, l15 = lane & 15;
    int wr = wid >> 2, wc = wid & 3;           // wave tile 128x64
    int lin = blockIdx.y * 12 + blockIdx.x;    // 384 blocks, 384%8==0
    int swz = (lin & 7) * 48 + (lin >> 3);     // bijective XCD swizzle
    int m0 = (swz / 12) * 256, n0 = (swz % 12) * 256;
    int rsw = ((l15 >> 1) & 3) << 3;           // read-side chunk XOR (shorts)

    const short* Ag = A + (long)m0 * 1024;
    const short* Bg = Bt + (long)n0 * 1024;

    f32x4 acc[8][4] = {};

    // prologue: tiles 0,1 in flight (16 loads); wait tile0 (oldest 8)
    stage256(Ag, Bg, 0, smem, tid, wid);
    stage256(Ag, Bg, 64, smem + 32768, tid, wid);
    asm volatile("s_waitcnt vmcnt(8)" ::: "memory");
    __builtin_amdgcn_s_barrier();

    for (int t = 0; t < NT; ++t) {
        const short* sA = smem + (t & 1) * 32768;
        const short* sB = sA + 16384;
        int qoff = (quad << 3) ^ rsw;  // swizzled chunk offset in shorts
        // ks = 0 fragments + MFMA
        bh8 a0[8], b0[4];
#pragma unroll
        for (int mi = 0; mi < 8; ++mi)
            a0[mi] = *(const bh8*)(sA + (wr * 128 + mi * 16 + l15) * 32 + qoff);
#pragma unroll
        for (int ni = 0; ni < 4; ++ni)
            b0[ni] = *(const bh8*)(sB + (wc * 64 + ni * 16 + l15) * 32 + qoff);
        __builtin_amdgcn_s_setprio(1);
#pragma unroll
        for (int mi = 0; mi < 8; ++mi)
#pragma unroll
            for (int ni = 0; ni < 4; ++ni)
                acc[mi][ni] = __builtin_amdgcn_mfma_f32_16x16x32_bf16(a0[mi], b0[ni], acc[mi][ni], 0, 0, 0);
        __builtin_amdgcn_s_setprio(0);
        // ks = 1 fragments
        bh8 a1[8], b1[4];
#pragma unroll
        for (int mi = 0; mi < 8; ++mi)
            a1[mi] = *(const bh8*)(sA + 8192 + (wr * 128 + mi * 16 + l15) * 32 + qoff);
#pragma unroll
        for (int ni = 0; ni < 4; ++ni)
            b1[ni] = *(const bh8*)(sB + 8192 + (wc * 64 + ni * 16 + l15) * 32 + qoff);
        // all reads of this buffer done (this wave: lgkm; all waves: barrier)
        asm volatile("s_waitcnt lgkmcnt(0)" ::: "memory");
        __builtin_amdgcn_sched_barrier(0);
        __builtin_amdgcn_s_barrier();
        // overwrite-stage tile t+2 into the buffer just vacated
        if (t + 2 < NT)
            stage256(Ag, Bg, (t + 2) << 6, smem + (t & 1) * 32768, tid, wid);
        __builtin_amdgcn_s_setprio(1);
#pragma unroll
        for (int mi = 0; mi < 8; ++mi)
#pragma unroll
            for (int ni = 0; ni < 4; ++ni)
                acc[mi][ni] = __builtin_amdgcn_mfma_f32_16x16x32_bf16(a1[mi], b1[ni], acc[mi][ni], 0, 0, 0);
        __builtin_amdgcn_s_setprio(0);
        // tile t+1 must be landed before next iter reads it:
        // in-flight = {t+1:8, t+2:8} -> vmcnt(8); tail: only {t+1:8} -> vmcnt(0)
        if (t + 2 < NT)      { asm volatile("s_waitcnt vmcnt(8)" ::: "memory"); }
        else if (t + 1 < NT) { asm volatile("s_waitcnt vmcnt(0)" ::: "memory"); }
        __builtin_amdgcn_s_barrier();
    }

    // epilogue: repack 256x256 through LDS (reuses staging space)
    __syncthreads();
    bool isV = (n0 >= 2048);
    if (!isV) {
#pragma unroll
        for (int mi = 0; mi < 8; ++mi)
#pragma unroll
            for (int ni = 0; ni < 4; ++ni) {
                int r = wr * 128 + mi * 16 + quad * 4;
                int c = wc * 64 + ni * 16 + l15;
#pragma unroll
                for (int reg = 0; reg < 4; ++reg)
                    smem[(r + reg) * 256 + c] = f2bf(acc[mi][ni][reg]);  // [row][col]
            }
    } else {
#pragma unroll
        for (int mi = 0; mi < 8; ++mi)
#pragma unroll
            for (int ni = 0; ni < 4; ++ni) {
                int r = wr * 128 + mi * 16 + quad * 4;
                int c = wc * 64 + ni * 16 + l15;
                unsigned lo = pk2bf(acc[mi][ni][0], acc[mi][ni][1]);
                unsigned hi = pk2bf(acc[mi][ni][2], acc[mi][ni][3]);
                uint2 uu = {lo, hi};
                *(bh4*)(smem + c * 256 + r) = __builtin_bit_cast(bh4, uu);  // [col][row]
            }
    }
    __syncthreads();
    int bb = m0 >> 11, sbase = m0 & 2047;
#pragma unroll
    for (int j = 0; j < 16; ++j) {
        int cj = j * 512 + tid;
        int i0 = cj >> 5, i1 = (cj & 31) << 3;
        bh8 v = *(const bh8*)(smem + i0 * 256 + i1);
        if (isV) {
            int cc = n0 - 2048 + i0;
            int h = cc >> 6, d = cc & 63;
            *(bh8*)(vt + ((long)(bb * NH_ + h) * HD_ + d) * S_ + sbase + i1) = v;
        } else {
            *(bh8*)(qk + (long)(m0 + i0) * 2048 + n0 + i1) = v;
        }
    }
}

// --------------------- out GEMM (R4 128x128 core + swizzle fix) ------------
__global__ __launch_bounds__(256, 2) void gemm_out(
    const short* __restrict__ A, const short* __restrict__ Bt,
    int N, int K, const float* __restrict__ bias, float* __restrict__ out) {
    __shared__ short smem[128 * 136];
    short* sA[2] = { smem, smem + 4096 };
    short* sB[2] = { smem + 8192, smem + 12288 };
    int tid = threadIdx.x;
    int lane = tid & 63, wid = tid >> 6;
    int quad = lane >> 4, l15 = lane & 15;
    int wy = wid >> 1, wx = wid & 1;
    int m0 = blockIdx.y * 128, n0 = blockIdx.x * 128;
    int rsw = ((l15 >> 1) & 3) << 3;  // read-side chunk XOR (shorts)

    f32x4 acc[4][4] = {};
    const short* Ag = A + (long)m0 * K;
    const short* Bg = Bt + (long)n0 * K;

    for (int k0 = 0; k0 < K; k0 += 64) {
#pragma unroll
        for (int half = 0; half < 2; ++half) {
#pragma unroll
            for (int i = 0; i < 2; ++i) {
                int flat = i * 256 + tid;
                int r = flat >> 2;
                int c = ((flat & 3) ^ ((flat >> 3) & 3)) << 3;  // pre-swizzled src
                __builtin_amdgcn_global_load_lds(
                    (const __attribute__((address_space(1))) void*)(Ag + (long)r * K + k0 + half * 32 + c),
                    (__attribute__((address_space(3))) void*)(sA[half] + i * 2048 + wid * 512),
                    16, 0, 0);
                __builtin_amdgcn_global_load_lds(
                    (const __attribute__((address_space(1))) void*)(Bg + (long)r * K + k0 + half * 32 + c),
                    (__attribute__((address_space(3))) void*)(sB[half] + i * 2048 + wid * 512),
                    16, 0, 0);
            }
        }
        __syncthreads();
#pragma unroll
        for (int half = 0; half < 2; ++half) {
            bh8 af[4], bfr[4];
            int qoff = (quad << 3) ^ rsw;
#pragma unroll
            for (int mi = 0; mi < 4; ++mi)
                af[mi] = *(const bh8*)(sA[half] + (wy * 64 + mi * 16 + l15) * 32 + qoff);
#pragma unroll
            for (int ni = 0; ni < 4; ++ni)
                bfr[ni] = *(const bh8*)(sB[half] + (wx * 64 + ni * 16 + l15) * 32 + qoff);
#pragma unroll
            for (int mi = 0; mi < 4; ++mi)
#pragma unroll
                for (int ni = 0; ni < 4; ++ni)
                    acc[mi][ni] = __builtin_amdgcn_mfma_f32_16x16x32_bf16(af[mi], bfr[ni], acc[mi][ni], 0, 0, 0);
        }
        __syncthreads();
    }

#pragma unroll
    for (int mi = 0; mi < 4; ++mi)
#pragma unroll
        for (int ni = 0; ni < 4; ++ni) {
            int gc = n0 + wx * 64 + ni * 16 + l15;
            float bv = bias[gc];
#pragma unroll
            for (int reg = 0; reg < 4; ++reg) {
                int gr = m0 + wy * 64 + mi * 16 + quad * 4 + reg;
                out[(long)gr * N + gc] = acc[mi][ni][reg] + bv;
            }
        }
}

// ---------------------------- flash attention ------------------------------
// R4 version (best measured): 64 q-rows/wave, 4 waves, grid (64,8) = 512
// blocks = 2/CU. V stored column-permuted in LDS: s=(pr,q16,quad,e) ->
// idx=(pr,quad,q16,e) so the PV B-fragment is one ds_read_b128.
__global__ __launch_bounds__(256, 2) void attn_fwd(
    const short* __restrict__ QK, const short* __restrict__ Vtw,
    short* __restrict__ Aout) {
    __shared__ short lK[2][64 * 72];
    __shared__ short lV[2][64 * 72];
    int tid = threadIdx.x;
    int lane = tid & 63, w = tid >> 6;
    int quad = lane >> 4, l15 = lane & 15;
    int p = blockIdx.x;
    int b = p >> 4, h = p & 15;
    int qbase = blockIdx.y * 256 + w * 64;

    const short* Kb = QK + (long)b * S_ * 2048 + 1024 + h * HD_;
    const short* Vb = Vtw + (long)p * HD_ * S_;

    // staging geometry, hoisted: thread stages rows r0 and r0+32, 8 cols each
    int r0 = tid >> 3, g = tid & 7, c = g << 3;
    int voff = (g >> 2) * 32 + (g & 1) * 16 + ((g >> 1) & 1) * 4;  // perm dest
    const short* Kp0 = Kb + (long)r0 * 2048 + c;      // + j0*2048 per tile
    const short* Kp1 = Kp0 + 32l * 2048;
    const short* Vp0 = Vb + (long)r0 * S_ + c;        // + j0 per tile
    const short* Vp1 = Vp0 + 32l * S_;

    // Q fragments (pre-scaled by 0.125*log2e at weight-transpose time)
    bh8 qf[4][2];
#pragma unroll
    for (int mi = 0; mi < 4; ++mi)
#pragma unroll
        for (int ks = 0; ks < 2; ++ks)
            qf[mi][ks] = *(const bh8*)(QK + (long)(b * S_ + qbase + mi * 16 + l15) * 2048
                                       + h * HD_ + ks * 32 + quad * 8);

    f32x4 o[4][4] = {};
    f32x4 ls[4] = {};
    const bh8 ones = {0x3F80, 0x3F80, 0x3F80, 0x3F80, 0x3F80, 0x3F80, 0x3F80, 0x3F80};

    int cnt = g_tl[b * 33];
    int e0 = g_tl[b * 33 + 1];
    int j0 = (e0 & 0xffff) << 6, flag = e0 >> 16;
    bh8 kp[2], vp[2];
    kp[0] = *(const bh8*)(Kp0 + (long)j0 * 2048);
    kp[1] = *(const bh8*)(Kp1 + (long)j0 * 2048);
    vp[0] = *(const bh8*)(Vp0 + j0);
    vp[1] = *(const bh8*)(Vp1 + j0);
    {
        *(bh8*)(lK[0] + r0 * 72 + c) = kp[0];
        *(bh8*)(lK[0] + (r0 + 32) * 72 + c) = kp[1];
        *(bh4*)(lV[0] + r0 * 72 + voff)            = __builtin_shufflevector(vp[0], vp[0], 0, 1, 2, 3);
        *(bh4*)(lV[0] + r0 * 72 + voff + 8)        = __builtin_shufflevector(vp[0], vp[0], 4, 5, 6, 7);
        *(bh4*)(lV[0] + (r0 + 32) * 72 + voff)     = __builtin_shufflevector(vp[1], vp[1], 0, 1, 2, 3);
        *(bh4*)(lV[0] + (r0 + 32) * 72 + voff + 8) = __builtin_shufflevector(vp[1], vp[1], 4, 5, 6, 7);
    }
    int cur = 0;

    for (int it = 0; it < cnt; ++it) {
        __syncthreads();  // buf[cur] writes visible; prior readers of buf[cur^1] done
        bool more = (it + 1 < cnt);
        int nj0 = 0, nflag = 0;
        if (more) {
            int en = g_tl[b * 33 + 2 + it];
            nj0 = (en & 0xffff) << 6; nflag = en >> 16;
            kp[0] = *(const bh8*)(Kp0 + (long)nj0 * 2048);   // prefetch overlaps
            kp[1] = *(const bh8*)(Kp1 + (long)nj0 * 2048);   // compute below
            vp[0] = *(const bh8*)(Vp0 + nj0);
            vp[1] = *(const bh8*)(Vp1 + nj0);
        }
        const short* ck = lK[cur];
        const short* cv = lV[cur];

        // S^T = K @ Q^T per 16-key subtile; exp2 -> P fragments in A-layout
        bh4 pf[4][4];  // [nj][mi]
#pragma unroll
        for (int nj = 0; nj < 4; ++nj) {
            f32x4 scn[4] = {};
#pragma unroll
            for (int ks = 0; ks < 2; ++ks) {
                bh8 kf = *(const bh8*)(ck + (nj * 16 + l15) * 72 + ks * 32 + quad * 8);
#pragma unroll
                for (int mi = 0; mi < 4; ++mi)
                    scn[mi] = __builtin_amdgcn_mfma_f32_16x16x32_bf16(kf, qf[mi][ks], scn[mi], 0, 0, 0);
            }
            if (flag == 1) {
                f32x4 bb = *(const f32x4*)(g_biasf + b * S_ + j0 + nj * 16 + quad * 4);
#pragma unroll
                for (int mi = 0; mi < 4; ++mi) {
#pragma unroll
                    for (int r = 0; r < 4; ++r) scn[mi][r] += bb[r];
                }
            }
#pragma unroll
            for (int mi = 0; mi < 4; ++mi) {
                unsigned u0 = pk2bf(__builtin_amdgcn_exp2f(scn[mi][0]),
                                    __builtin_amdgcn_exp2f(scn[mi][1]));
                unsigned u1 = pk2bf(__builtin_amdgcn_exp2f(scn[mi][2]),
                                    __builtin_amdgcn_exp2f(scn[mi][3]));
                uint2 uu = {u0, u1};
                pf[nj][mi] = __builtin_bit_cast(bh4, uu);
            }
        }

        // O += P @ V, ls += P @ ones (two 16-key subtiles per K=32 mfma)
#pragma unroll
        for (int pr = 0; pr < 2; ++pr) {
            int njA = 2 * pr, njB = 2 * pr + 1;
            bh8 a[4];
#pragma unroll
            for (int mi = 0; mi < 4; ++mi)
                a[mi] = __builtin_shufflevector(pf[njA][mi], pf[njB][mi], 0, 1, 2, 3, 4, 5, 6, 7);
            __builtin_amdgcn_s_setprio(1);
#pragma unroll
            for (int mi = 0; mi < 4; ++mi)
                ls[mi] = __builtin_amdgcn_mfma_f32_16x16x32_bf16(a[mi], ones, ls[mi], 0, 0, 0);
#pragma unroll
            for (int nd = 0; nd < 4; ++nd) {
                // permuted layout: one b128 = old concat(v0, v1)
                bh8 vf = *(const bh8*)(cv + (nd * 16 + l15) * 72 + pr * 32 + quad * 8);
#pragma unroll
                for (int mi = 0; mi < 4; ++mi)
                    o[mi][nd] = __builtin_amdgcn_mfma_f32_16x16x32_bf16(a[mi], vf, o[mi][nd], 0, 0, 0);
            }
            __builtin_amdgcn_s_setprio(0);
        }

        if (more) {
            short* lk = lK[cur ^ 1];
            short* lv = lV[cur ^ 1];
            *(bh8*)(lk + r0 * 72 + c) = kp[0];
            *(bh8*)(lk + (r0 + 32) * 72 + c) = kp[1];
            *(bh4*)(lv + r0 * 72 + voff)            = __builtin_shufflevector(vp[0], vp[0], 0, 1, 2, 3);
            *(bh4*)(lv + r0 * 72 + voff + 8)        = __builtin_shufflevector(vp[0], vp[0], 4, 5, 6, 7);
            *(bh4*)(lv + (r0 + 32) * 72 + voff)     = __builtin_shufflevector(vp[1], vp[1], 0, 1, 2, 3);
            *(bh4*)(lv + (r0 + 32) * 72 + voff + 8) = __builtin_shufflevector(vp[1], vp[1], 4, 5, 6, 7);
        }
        j0 = nj0; flag = nflag; cur ^= 1;
    }

    // Aout[b][s][h*64+d] = O * (1/ls)  (rcp is fine: output is bf16-rounded)
#pragma unroll
    for (int mi = 0; mi < 4; ++mi)
#pragma unroll
        for (int reg = 0; reg < 4; ++reg) {
            float inv = __builtin_amdgcn_rcpf(ls[mi][reg]);
            int s = qbase + mi * 16 + quad * 4 + reg;
#pragma unroll
            for (int nd = 0; nd < 4; ++nd) {
                int col = h * HD_ + nd * 16 + l15;
                Aout[((long)b * S_ + s) * H_ + col] = f2bf(o[mi][nd][reg] * inv);
            }
        }
}

// ------------------------------- launcher ----------------------------------
extern "C" void kernel_launch(void* const* d_in, const int* in_sizes, int n_in,
                              void* d_out, int out_size, void* d_ws, size_t ws_size,
                              hipStream_t stream) {
    const float* hidden = (const float*)d_in[0];
    const int* mask = (const int*)d_in[1];
    const float* Wqkv = (const float*)d_in[2];
    const float* Wout = (const float*)d_in[3];
    const float* bout = (const float*)d_in[4];
    float* out = (float*)d_out;

    char* ws = (char*)d_ws;
    const size_t XBF = 0;                       // 16 MB (Aout alias)
    const size_t WQKVT = 16777216;              // 6 MB
    const size_t WOUTT = WQKVT + 6291456;       // 2 MB
    const size_t QKO = WOUTT + 2097152;         // 32 MB: QK[8192][2048]
    const size_t VT = QKO + 33554432;           // 16 MB: Vt (end 72 MB)

    short* Xbf = (short*)(ws + XBF);
    short* WqkvT = (short*)(ws + WQKVT);
    short* WoutT = (short*)(ws + WOUTT);
    short* QK = (short*)(ws + QKO);
    short* Vt = (short*)(ws + VT);
    short* Aout = Xbf;                            // Xbf dead after QKV GEMM

    const float Cs = 0.18033688011112042f;  // (1/8) * log2(e), folded into Q

    // fused prep: cvt + Wqkv^T + Wout^T + bias + tilelist (1 launch)
    prep_all<<<dim3(12324), dim3(256), 0, stream>>>(
        hidden, Wqkv, Wout, mask, Xbf, WqkvT, WoutT, Cs);

    // QKV projection: M=8192, N=3072, K=1024 (256^2 deep-pipelined, swizzled)
    gemm_qkv<<<dim3(12, 32), dim3(512), 0, stream>>>(Xbf, WqkvT, QK, Vt);

    attn_fwd<<<dim3(64, 8), dim3(256), 0, stream>>>(QK, Vt, Aout);

    // Output projection: M=8192, N=1024, K=1024 (+bias, fp32 out)
    gemm_out<<<dim3(8, 64), dim3(256), 0, stream>>>(
        Aout, WoutT, H_, H_, bout, out);
}

// Round 10
// 251.966 us; speedup vs baseline: 1.0629x; 1.0488x over previous
//
#include <hip/hip_runtime.h>

// ---------------------------------------------------------------------------
// MultiHeadAttention: B=4, S=2048, NH=16, HD=64, H=1024
// Pipeline (all bf16 MFMA, fp32 accumulate):
//   1) prep_all (fused): X -> bf16; Wqkv^T -> bf16 with softmax scale
//      (0.125*log2e) folded into Q columns; Wout^T -> bf16; mask -> bias;
//      mask -> compacted tile list (bias/tl in __device__ globals).
//   2) QKV = X @ Wqkv: 128x128 tile, BK=64 (R4 structure - best measured) +
//      R10 chunk XOR-swizzle (chunk ^= (row>>1)&3) fixing the 4-way bank
//      conflict on b128 fragment reads that R8's PMC exposed (7.2M) in this
//      [row][32-short] layout family. Swizzle both-sides: pre-swizzled
//      global SOURCE col + linear LDS dest (gload_lds) + XOR'd read offset.
//   3) flash attention (R4 version - best measured 82 us, pinned):
//      4 waves/256thr, 64 q-rows/wave, grid (64,8); operand-swap
//      (S^T = mfma(K,Q)); compacted tile list; 1-barrier double-buffered KV
//      staging w/ register prefetch; V column-permuted in LDS (PV B-frag =
//      1 ds_read_b128); packed bf16 P; MFMA row-sums; rcp epilogue.
//   4) out = Aout @ Wout + bout (same 128^2 core, mode 1)
// History: R1/R2 (attn occupancy variants) regressed; R5 (no-LDS attn)
// latency disaster; R7 (2ph counted-vmcnt @128^2) null per catalog regime
// gate; R8/R9 (256^2 deep pipeline) net loss - 384 tiles = 1.5 dispatch
// rounds + coarse phase-split (m196). 128^2 everywhere + fixes = best.
// Workspace 72 MB: Xbf 16 (Aout alias) | WqkvT 6 | WoutT 2 | QK 32 | Vt 16
// ---------------------------------------------------------------------------

typedef short bh8 __attribute__((ext_vector_type(8)));
typedef short bh4 __attribute__((ext_vector_type(4)));
typedef float f32x4 __attribute__((ext_vector_type(4)));

#define B_ 4
#define S_ 2048
#define NH_ 16
#define HD_ 64
#define H_ 1024

__device__ float g_biasf[B_ * S_];
__device__ int g_tl[B_ * 33];

__device__ inline short f2bf(float f) {
    unsigned u = __builtin_bit_cast(unsigned, f);
    u = (u + 0x7fffu + ((u >> 16) & 1u)) >> 16;  // RTNE
    return (short)u;
}

// pack two f32 -> two bf16 in one dword (low = a, high = b)
__device__ inline unsigned pk2bf(float a, float b) {
#if __has_builtin(__builtin_amdgcn_cvt_pk_bf16_f32)
    auto r = __builtin_amdgcn_cvt_pk_bf16_f32(a, b);
    return __builtin_bit_cast(unsigned, r);
#else
    unsigned ua = __builtin_bit_cast(unsigned, a) + 0x8000u;  // round-half-up
    unsigned ub = __builtin_bit_cast(unsigned, b) + 0x8000u;
    return __builtin_amdgcn_perm(ub, ua, 0x07060302);  // [ua2,ua3,ub2,ub3]
#endif
}

// ------------------- fused prep: cvt + 2 transposes + bias + tilelist ------
// block ranges: [0,8192) cvt X | [8192,11264) Wqkv^T | [11264,12288) Wout^T |
//               [12288,12320) bias | [12320,12324) tilelist
__global__ void prep_all(const float* __restrict__ hidden, const float* __restrict__ Wqkv,
                         const float* __restrict__ Wout, const int* __restrict__ mask,
                         short* __restrict__ Xbf, short* __restrict__ WqkvT,
                         short* __restrict__ WoutT, float qs) {
    __shared__ float tile[32][33];
    int bi = blockIdx.x, tid = threadIdx.x;

    if (bi < 8192) {  // ---- X fp32 -> bf16
        int i = (bi * 256 + tid) * 4;
        float4 v = *(const float4*)(hidden + i);
        union { short s[4]; unsigned long long u; } r;
        r.s[0] = f2bf(v.x); r.s[1] = f2bf(v.y); r.s[2] = f2bf(v.z); r.s[3] = f2bf(v.w);
        *(unsigned long long*)(Xbf + i) = r.u;
        return;
    }
    if (bi < 12288) {  // ---- weight transpose+cvt (32x32 tiles, 256 thr)
        const float* in; short* out; int N, qcols, idx;
        if (bi < 11264) { in = Wqkv; out = WqkvT; N = 3 * H_; qcols = H_; idx = bi - 8192;
        } else          { in = Wout; out = WoutT; N = H_;    qcols = 0;  idx = bi - 11264; }
        int xt = (bi < 11264) ? 96 : 32;
        int n0 = (idx % xt) * 32, k0 = (idx / xt) * 32;
        int tx = tid & 31, ty = tid >> 5;  // (32,8)
#pragma unroll
        for (int i = 0; i < 32; i += 8)
            tile[ty + i][tx] = in[(long)(k0 + ty + i) * N + n0 + tx];
        __syncthreads();
#pragma unroll
        for (int i = 0; i < 32; i += 8) {
            int n = n0 + ty + i;
            float v = tile[tx][ty + i];
            if (n < qcols) v *= qs;
            out[(long)n * H_ + k0 + tx] = f2bf(v);
        }
        return;
    }
    if (bi < 12320) {  // ---- mask -> additive bias
        int i = (bi - 12288) * 256 + tid;
        g_biasf[i] = mask[i] ? 0.0f : -1e30f;
        return;
    }
    {  // ---- tilelist: 4 blocks, wave 0 only (ballot is wave-wide = 64)
        int b = bi - 12320;
        if (tid < 64) {
            int t = tid, flag = 0;
            if (t < 32) {
                bool anyA = false, anyM = false;
                for (int i = 0; i < 64; ++i) {
                    int m = mask[b * S_ + t * 64 + i];
                    anyA |= (m != 0); anyM |= (m == 0);
                }
                flag = anyA ? (anyM ? 1 : 2) : 0;
            }
            unsigned long long act = __ballot(flag != 0);
            int pos = __popcll(act & ((1ull << t) - 1ull));
            if (flag) g_tl[b * 33 + 1 + pos] = t | (flag << 16);
            if (t == 0) g_tl[b * 33] = __popcll(act);
        }
    }
}

// ------------------------------- GEMM core ---------------------------------
// R4 structure (single-buffered BK=64, 2x32 panels, gload_lds w16) + R10
// chunk XOR-swizzle. LDS[row][c] holds global[row][c ^ ((row>>1)&3)]
// (involution; source pre-swizzled, LDS dest linear). Fragment reads XOR
// the chunk -> per-8-lane beat banks (row%2)*16 + (quad^((row>>1)&3))*4
// cover all 32: conflict-free (was 4-way, R8 PMC: 7.2M).
__global__ __launch_bounds__(256, 2) void gemm_bf16(
    const short* __restrict__ A, const short* __restrict__ Bt,
    int M, int N, int K, int mode,
    short* __restrict__ qk, short* __restrict__ vt,
    const float* __restrict__ bias, float* __restrict__ out) {
    __shared__ short smem[128 * 136];
    short* sA[2] = { smem, smem + 4096 };
    short* sB[2] = { smem + 8192, smem + 12288 };
    int tid = threadIdx.x;
    int lane = tid & 63, wid = tid >> 6;
    int quad = lane >> 4, l15 = lane & 15;
    int wy = wid >> 1, wx = wid & 1;
    int m0 = blockIdx.y * 128, n0 = blockIdx.x * 128;
    int rsw = ((l15 >> 1) & 3) << 3;  // read-side chunk XOR (shorts)

    f32x4 acc[4][4] = {};
    const short* Ag = A + (long)m0 * K;
    const short* Bg = Bt + (long)n0 * K;

    for (int k0 = 0; k0 < K; k0 += 64) {
#pragma unroll
        for (int half = 0; half < 2; ++half) {
#pragma unroll
            for (int i = 0; i < 2; ++i) {
                int flat = i * 256 + tid;
                int r = flat >> 2;
                int c = ((flat & 3) ^ ((flat >> 3) & 3)) << 3;  // pre-swizzled src
                __builtin_amdgcn_global_load_lds(
                    (const __attribute__((address_space(1))) void*)(Ag + (long)r * K + k0 + half * 32 + c),
                    (__attribute__((address_space(3))) void*)(sA[half] + i * 2048 + wid * 512),
                    16, 0, 0);
                __builtin_amdgcn_global_load_lds(
                    (const __attribute__((address_space(1))) void*)(Bg + (long)r * K + k0 + half * 32 + c),
                    (__attribute__((address_space(3))) void*)(sB[half] + i * 2048 + wid * 512),
                    16, 0, 0);
            }
        }
        __syncthreads();
#pragma unroll
        for (int half = 0; half < 2; ++half) {
            bh8 af[4], bfr[4];
            int qoff = (quad << 3) ^ rsw;  // swizzled chunk offset (shorts)
#pragma unroll
            for (int mi = 0; mi < 4; ++mi)
                af[mi] = *(const bh8*)(sA[half] + (wy * 64 + mi * 16 + l15) * 32 + qoff);
#pragma unroll
            for (int ni = 0; ni < 4; ++ni)
                bfr[ni] = *(const bh8*)(sB[half] + (wx * 64 + ni * 16 + l15) * 32 + qoff);
#pragma unroll
            for (int mi = 0; mi < 4; ++mi)
#pragma unroll
                for (int ni = 0; ni < 4; ++ni)
                    acc[mi][ni] = __builtin_amdgcn_mfma_f32_16x16x32_bf16(af[mi], bfr[ni], acc[mi][ni], 0, 0, 0);
        }
        __syncthreads();
    }

    if (mode == 0) {
        bool isV = (n0 >= 2048);
#pragma unroll
        for (int mi = 0; mi < 4; ++mi)
#pragma unroll
            for (int ni = 0; ni < 4; ++ni) {
                int c = wx * 64 + ni * 16 + l15;
                int rb = wy * 64 + mi * 16 + quad * 4;
                if (isV) {
                    // [col][row]: 4 regs contiguous -> one 8B packed store
                    unsigned lo = pk2bf(acc[mi][ni][0], acc[mi][ni][1]);
                    unsigned hi = pk2bf(acc[mi][ni][2], acc[mi][ni][3]);
                    uint2 uu = {lo, hi};
                    *(bh4*)(smem + c * 136 + rb) = __builtin_bit_cast(bh4, uu);
                } else {
#pragma unroll
                    for (int reg = 0; reg < 4; ++reg)
                        smem[(rb + reg) * 136 + c] = f2bf(acc[mi][ni][reg]);  // [row][col]
                }
            }
        __syncthreads();
        int b = m0 >> 11, sbase = m0 & 2047;
#pragma unroll
        for (int j = 0; j < 8; ++j) {
            int f = (j * 256 + tid) * 8;
            int i0 = f >> 7, i1 = f & 127;
            bh8 v = *(const bh8*)(smem + i0 * 136 + i1);
            if (isV) {
                int cc = n0 - 2048 + i0;
                int h = cc >> 6, d = cc & 63;
                *(bh8*)(vt + ((long)(b * NH_ + h) * HD_ + d) * S_ + sbase + i1) = v;
            } else {
                *(bh8*)(qk + (long)(m0 + i0) * 2048 + n0 + i1) = v;
            }
        }
    } else {
#pragma unroll
        for (int mi = 0; mi < 4; ++mi)
#pragma unroll
            for (int ni = 0; ni < 4; ++ni) {
                int gc = n0 + wx * 64 + ni * 16 + l15;
                float bv = bias[gc];
#pragma unroll
                for (int reg = 0; reg < 4; ++reg) {
                    int gr = m0 + wy * 64 + mi * 16 + quad * 4 + reg;
                    out[(long)gr * N + gc] = acc[mi][ni][reg] + bv;
                }
            }
    }
}

// ---------------------------- flash attention ------------------------------
// R4 version (best measured): 64 q-rows/wave, 4 waves, grid (64,8) = 512
// blocks = 2/CU. V stored column-permuted in LDS: s=(pr,q16,quad,e) ->
// idx=(pr,quad,q16,e) so the PV B-fragment is one ds_read_b128.
__global__ __launch_bounds__(256, 2) void attn_fwd(
    const short* __restrict__ QK, const short* __restrict__ Vtw,
    short* __restrict__ Aout) {
    __shared__ short lK[2][64 * 72];
    __shared__ short lV[2][64 * 72];
    int tid = threadIdx.x;
    int lane = tid & 63, w = tid >> 6;
    int quad = lane >> 4, l15 = lane & 15;
    int p = blockIdx.x;
    int b = p >> 4, h = p & 15;
    int qbase = blockIdx.y * 256 + w * 64;

    const short* Kb = QK + (long)b * S_ * 2048 + 1024 + h * HD_;
    const short* Vb = Vtw + (long)p * HD_ * S_;

    // staging geometry, hoisted: thread stages rows r0 and r0+32, 8 cols each
    int r0 = tid >> 3, g = tid & 7, c = g << 3;
    int voff = (g >> 2) * 32 + (g & 1) * 16 + ((g >> 1) & 1) * 4;  // perm dest
    const short* Kp0 = Kb + (long)r0 * 2048 + c;      // + j0*2048 per tile
    const short* Kp1 = Kp0 + 32l * 2048;
    const short* Vp0 = Vb + (long)r0 * S_ + c;        // + j0 per tile
    const short* Vp1 = Vp0 + 32l * S_;

    // Q fragments (pre-scaled by 0.125*log2e at weight-transpose time)
    bh8 qf[4][2];
#pragma unroll
    for (int mi = 0; mi < 4; ++mi)
#pragma unroll
        for (int ks = 0; ks < 2; ++ks)
            qf[mi][ks] = *(const bh8*)(QK + (long)(b * S_ + qbase + mi * 16 + l15) * 2048
                                       + h * HD_ + ks * 32 + quad * 8);

    f32x4 o[4][4] = {};
    f32x4 ls[4] = {};
    const bh8 ones = {0x3F80, 0x3F80, 0x3F80, 0x3F80, 0x3F80, 0x3F80, 0x3F80, 0x3F80};

    int cnt = g_tl[b * 33];
    int e0 = g_tl[b * 33 + 1];
    int j0 = (e0 & 0xffff) << 6, flag = e0 >> 16;
    bh8 kp[2], vp[2];
    kp[0] = *(const bh8*)(Kp0 + (long)j0 * 2048);
    kp[1] = *(const bh8*)(Kp1 + (long)j0 * 2048);
    vp[0] = *(const bh8*)(Vp0 + j0);
    vp[1] = *(const bh8*)(Vp1 + j0);
    {
        *(bh8*)(lK[0] + r0 * 72 + c) = kp[0];
        *(bh8*)(lK[0] + (r0 + 32) * 72 + c) = kp[1];
        *(bh4*)(lV[0] + r0 * 72 + voff)            = __builtin_shufflevector(vp[0], vp[0], 0, 1, 2, 3);
        *(bh4*)(lV[0] + r0 * 72 + voff + 8)        = __builtin_shufflevector(vp[0], vp[0], 4, 5, 6, 7);
        *(bh4*)(lV[0] + (r0 + 32) * 72 + voff)     = __builtin_shufflevector(vp[1], vp[1], 0, 1, 2, 3);
        *(bh4*)(lV[0] + (r0 + 32) * 72 + voff + 8) = __builtin_shufflevector(vp[1], vp[1], 4, 5, 6, 7);
    }
    int cur = 0;

    for (int it = 0; it < cnt; ++it) {
        __syncthreads();  // buf[cur] writes visible; prior readers of buf[cur^1] done
        bool more = (it + 1 < cnt);
        int nj0 = 0, nflag = 0;
        if (more) {
            int en = g_tl[b * 33 + 2 + it];
            nj0 = (en & 0xffff) << 6; nflag = en >> 16;
            kp[0] = *(const bh8*)(Kp0 + (long)nj0 * 2048);   // prefetch overlaps
            kp[1] = *(const bh8*)(Kp1 + (long)nj0 * 2048);   // compute below
            vp[0] = *(const bh8*)(Vp0 + nj0);
            vp[1] = *(const bh8*)(Vp1 + nj0);
        }
        const short* ck = lK[cur];
        const short* cv = lV[cur];

        // S^T = K @ Q^T per 16-key subtile; exp2 -> P fragments in A-layout
        bh4 pf[4][4];  // [nj][mi]
#pragma unroll
        for (int nj = 0; nj < 4; ++nj) {
            f32x4 scn[4] = {};
#pragma unroll
            for (int ks = 0; ks < 2; ++ks) {
                bh8 kf = *(const bh8*)(ck + (nj * 16 + l15) * 72 + ks * 32 + quad * 8);
#pragma unroll
                for (int mi = 0; mi < 4; ++mi)
                    scn[mi] = __builtin_amdgcn_mfma_f32_16x16x32_bf16(kf, qf[mi][ks], scn[mi], 0, 0, 0);
            }
            if (flag == 1) {
                f32x4 bb = *(const f32x4*)(g_biasf + b * S_ + j0 + nj * 16 + quad * 4);
#pragma unroll
                for (int mi = 0; mi < 4; ++mi) {
#pragma unroll
                    for (int r = 0; r < 4; ++r) scn[mi][r] += bb[r];
                }
            }
#pragma unroll
            for (int mi = 0; mi < 4; ++mi) {
                unsigned u0 = pk2bf(__builtin_amdgcn_exp2f(scn[mi][0]),
                                    __builtin_amdgcn_exp2f(scn[mi][1]));
                unsigned u1 = pk2bf(__builtin_amdgcn_exp2f(scn[mi][2]),
                                    __builtin_amdgcn_exp2f(scn[mi][3]));
                uint2 uu = {u0, u1};
                pf[nj][mi] = __builtin_bit_cast(bh4, uu);
            }
        }

        // O += P @ V, ls += P @ ones (two 16-key subtiles per K=32 mfma)
#pragma unroll
        for (int pr = 0; pr < 2; ++pr) {
            int njA = 2 * pr, njB = 2 * pr + 1;
            bh8 a[4];
#pragma unroll
            for (int mi = 0; mi < 4; ++mi)
                a[mi] = __builtin_shufflevector(pf[njA][mi], pf[njB][mi], 0, 1, 2, 3, 4, 5, 6, 7);
            __builtin_amdgcn_s_setprio(1);
#pragma unroll
            for (int mi = 0; mi < 4; ++mi)
                ls[mi] = __builtin_amdgcn_mfma_f32_16x16x32_bf16(a[mi], ones, ls[mi], 0, 0, 0);
#pragma unroll
            for (int nd = 0; nd < 4; ++nd) {
                // permuted layout: one b128 = old concat(v0, v1)
                bh8 vf = *(const bh8*)(cv + (nd * 16 + l15) * 72 + pr * 32 + quad * 8);
#pragma unroll
                for (int mi = 0; mi < 4; ++mi)
                    o[mi][nd] = __builtin_amdgcn_mfma_f32_16x16x32_bf16(a[mi], vf, o[mi][nd], 0, 0, 0);
            }
            __builtin_amdgcn_s_setprio(0);
        }

        if (more) {
            short* lk = lK[cur ^ 1];
            short* lv = lV[cur ^ 1];
            *(bh8*)(lk + r0 * 72 + c) = kp[0];
            *(bh8*)(lk + (r0 + 32) * 72 + c) = kp[1];
            *(bh4*)(lv + r0 * 72 + voff)            = __builtin_shufflevector(vp[0], vp[0], 0, 1, 2, 3);
            *(bh4*)(lv + r0 * 72 + voff + 8)        = __builtin_shufflevector(vp[0], vp[0], 4, 5, 6, 7);
            *(bh4*)(lv + (r0 + 32) * 72 + voff)     = __builtin_shufflevector(vp[1], vp[1], 0, 1, 2, 3);
            *(bh4*)(lv + (r0 + 32) * 72 + voff + 8) = __builtin_shufflevector(vp[1], vp[1], 4, 5, 6, 7);
        }
        j0 = nj0; flag = nflag; cur ^= 1;
    }

    // Aout[b][s][h*64+d] = O * (1/ls)  (rcp is fine: output is bf16-rounded)
#pragma unroll
    for (int mi = 0; mi < 4; ++mi)
#pragma unroll
        for (int reg = 0; reg < 4; ++reg) {
            float inv = __builtin_amdgcn_rcpf(ls[mi][reg]);
            int s = qbase + mi * 16 + quad * 4 + reg;
#pragma unroll
            for (int nd = 0; nd < 4; ++nd) {
                int col = h * HD_ + nd * 16 + l15;
                Aout[((long)b * S_ + s) * H_ + col] = f2bf(o[mi][nd][reg] * inv);
            }
        }
}

// ------------------------------- launcher ----------------------------------
extern "C" void kernel_launch(void* const* d_in, const int* in_sizes, int n_in,
                              void* d_out, int out_size, void* d_ws, size_t ws_size,
                              hipStream_t stream) {
    const float* hidden = (const float*)d_in[0];
    const int* mask = (const int*)d_in[1];
    const float* Wqkv = (const float*)d_in[2];
    const float* Wout = (const float*)d_in[3];
    const float* bout = (const float*)d_in[4];
    float* out = (float*)d_out;

    char* ws = (char*)d_ws;
    const size_t XBF = 0;                       // 16 MB (Aout alias)
    const size_t WQKVT = 16777216;              // 6 MB
    const size_t WOUTT = WQKVT + 6291456;       // 2 MB
    const size_t QKO = WOUTT + 2097152;         // 32 MB: QK[8192][2048]
    const size_t VT = QKO + 33554432;           // 16 MB: Vt (end 72 MB)

    short* Xbf = (short*)(ws + XBF);
    short* WqkvT = (short*)(ws + WQKVT);
    short* WoutT = (short*)(ws + WOUTT);
    short* QK = (short*)(ws + QKO);
    short* Vt = (short*)(ws + VT);
    short* Aout = Xbf;                            // Xbf dead after QKV GEMM

    const float Cs = 0.18033688011112042f;  // (1/8) * log2(e), folded into Q

    // fused prep: cvt + Wqkv^T + Wout^T + bias + tilelist (1 launch)
    prep_all<<<dim3(12324), dim3(256), 0, stream>>>(
        hidden, Wqkv, Wout, mask, Xbf, WqkvT, WoutT, Cs);

    // QKV projection: M=8192, N=3072, K=1024
    gemm_bf16<<<dim3(24, 64), dim3(256), 0, stream>>>(
        Xbf, WqkvT, B_ * S_, 3 * H_, H_, 0, QK, Vt, nullptr, nullptr);

    attn_fwd<<<dim3(64, 8), dim3(256), 0, stream>>>(QK, Vt, Aout);

    // Output projection: M=8192, N=1024, K=1024 (+bias, fp32 out)
    gemm_bf16<<<dim3(8, 64), dim3(256), 0, stream>>>(
        Aout, WoutT, B_ * S_, H_, H_, 1, nullptr, nullptr, bout, out);
}